// Round 1
// baseline (659.059 us; speedup 1.0000x reference)
//
#include <hip/hip_runtime.h>
#include <math.h>

// Problem constants (B=2,S=2048 -> T=4096; D=H=1024; E=16; K=2; CF=1.25)
#define T_TOK 4096
#define DIM   1024
#define HID   1024
#define NE    16
#define CAP   640      // ceil(T*K/E*CF)
#define CBUF  1280     // K*CAP
#define BM 128
#define BN 128
#define BK 32
#define SAP 40         // LDS row stride in bf16 elems (32 + 8 pad -> 80B = 20 banks)

typedef __attribute__((ext_vector_type(8))) short short8;   // 8 bf16 (4 VGPRs)
typedef __attribute__((ext_vector_type(4))) float f32x4;    // MFMA accumulator

static __device__ __forceinline__ unsigned short f2bf(float f) {
    unsigned int u = __float_as_uint(f);
    u += 0x7fff + ((u >> 16) & 1);   // RNE
    return (unsigned short)(u >> 16);
}

// ---------------- x -> bf16 (with zero padding row at index T) ----------------
__global__ void convert_x_k(const float* __restrict__ x, unsigned short* __restrict__ xb) {
    int i = blockIdx.x * blockDim.x + threadIdx.x;  // group of 4 elems
    int base = i * 4;
    int row = base >> 10;
    ushort4 o;
    if (row < T_TOK) {
        float4 v = *(const float4*)(x + base);
        o.x = f2bf(v.x); o.y = f2bf(v.y); o.z = f2bf(v.z); o.w = f2bf(v.w);
    } else {
        o.x = 0; o.y = 0; o.z = 0; o.w = 0;
    }
    *(ushort4*)(xb + base) = o;
}

// ------------- weight fp32 [e][K][N] -> bf16 transposed [e][N][K] -------------
// K=N=1024 for all three tensors. 64x64 tiles via LDS.
__global__ void transpose_cvt_k(const float* __restrict__ W, unsigned short* __restrict__ Wt) {
    __shared__ unsigned short s[64][66];
    int e = blockIdx.z;
    const float* Wp = W + (size_t)e * DIM * HID;
    unsigned short* Wtp = Wt + (size_t)e * DIM * HID;
    int k0 = blockIdx.y * 64, n0 = blockIdx.x * 64;
    int tx = threadIdx.x & 15, ty = threadIdx.x >> 4;
    #pragma unroll
    for (int i = 0; i < 4; ++i) {
        int k = ty + i * 16;
        float4 v = *(const float4*)(Wp + (size_t)(k0 + k) * 1024 + n0 + tx * 4);
        s[k][tx*4+0] = f2bf(v.x); s[k][tx*4+1] = f2bf(v.y);
        s[k][tx*4+2] = f2bf(v.z); s[k][tx*4+3] = f2bf(v.w);
    }
    __syncthreads();
    #pragma unroll
    for (int i = 0; i < 4; ++i) {
        int n = ty + i * 16;
        ushort4 o;
        o.x = s[tx*4+0][n]; o.y = s[tx*4+1][n];
        o.z = s[tx*4+2][n]; o.w = s[tx*4+3][n];
        *(ushort4*)(Wtp + (size_t)(n0 + n) * 1024 + k0 + tx * 4) = o;
    }
}

// ---------------- router: logits, softmax, top-2 (one wave per token) ----------------
__global__ void router_k(const float* __restrict__ x, const float* __restrict__ rw,
                         int* __restrict__ route_e, float* __restrict__ route_w) {
    int t = blockIdx.x;
    int lane = threadIdx.x;
    const float* xr = x + (size_t)t * DIM + lane * 16;
    float4 xv0 = *(const float4*)(xr + 0);
    float4 xv1 = *(const float4*)(xr + 4);
    float4 xv2 = *(const float4*)(xr + 8);
    float4 xv3 = *(const float4*)(xr + 12);
    float xl[16] = {xv0.x, xv0.y, xv0.z, xv0.w, xv1.x, xv1.y, xv1.z, xv1.w,
                    xv2.x, xv2.y, xv2.z, xv2.w, xv3.x, xv3.y, xv3.z, xv3.w};
    float p[16];
    #pragma unroll
    for (int e = 0; e < 16; ++e) p[e] = 0.f;
    #pragma unroll
    for (int j = 0; j < 16; ++j) {
        const float4* rp = (const float4*)(rw + (size_t)(lane * 16 + j) * 16);
        float4 r0 = rp[0], r1 = rp[1], r2 = rp[2], r3 = rp[3];
        float xv = xl[j];
        p[0]  += xv * r0.x; p[1]  += xv * r0.y; p[2]  += xv * r0.z; p[3]  += xv * r0.w;
        p[4]  += xv * r1.x; p[5]  += xv * r1.y; p[6]  += xv * r1.z; p[7]  += xv * r1.w;
        p[8]  += xv * r2.x; p[9]  += xv * r2.y; p[10] += xv * r2.z; p[11] += xv * r2.w;
        p[12] += xv * r3.x; p[13] += xv * r3.y; p[14] += xv * r3.z; p[15] += xv * r3.w;
    }
    #pragma unroll
    for (int off = 32; off > 0; off >>= 1) {
        #pragma unroll
        for (int e = 0; e < 16; ++e) p[e] += __shfl_xor(p[e], off);
    }
    if (lane == 0) {
        float m = p[0];
        #pragma unroll
        for (int e = 1; e < 16; ++e) m = fmaxf(m, p[e]);
        float s = 0.f;
        #pragma unroll
        for (int e = 0; e < 16; ++e) s = s + __expf(p[e] - m);
        float v0 = -1e30f, v1 = -1e30f; int i0 = 0, i1 = 0;
        #pragma unroll
        for (int e = 0; e < 16; ++e) {
            float v = p[e];
            if (v > v0)      { v1 = v0; i1 = i0; v0 = v; i0 = e; }
            else if (v > v1) { v1 = v;  i1 = e; }
        }
        route_e[t*2+0] = i0;  route_e[t*2+1] = i1;
        route_w[t*2+0] = __expf(v0 - m) / s;
        route_w[t*2+1] = __expf(v1 - m) / s;
    }
}

// ------- dispatch build: keep (rank per (e,k) stream) + slot (per-e flat stream) -------
__global__ __launch_bounds__(1024)
void build_dispatch_k(const int* __restrict__ route_e, const float* __restrict__ route_w,
                      int* __restrict__ disp, float* __restrict__ wbuf, int* __restrict__ counts) {
    __shared__ unsigned char eidx[2 * T_TOK];
    __shared__ unsigned char keepf[2 * T_TOK];
    __shared__ int cnt2[32][33];   // (e,k) stream x 32 token-chunks of 128
    __shared__ int cnt3[16][65];   // expert x 64 flat-chunks of 128
    __shared__ int totals[16];
    int tid = threadIdx.x;
    for (int i = tid; i < 2 * T_TOK; i += 1024) eidx[i] = (unsigned char)route_e[i];
    __syncthreads();
    {   // per-(e,k) chunk counts
        int ek = tid >> 5, chunk = tid & 31;
        int e = ek >> 1, k = ek & 1;
        int base = chunk * 128, c = 0;
        for (int t = 0; t < 128; ++t) c += (eidx[(base + t) * 2 + k] == e);
        cnt2[ek][chunk] = c;
    }
    __syncthreads();
    if (tid < 32) {   // exclusive prefix per stream
        int s = 0;
        for (int c = 0; c < 32; ++c) { int v = cnt2[tid][c]; cnt2[tid][c] = s; s += v; }
    }
    __syncthreads();
    {   // assign keep = (rank < CAP)
        int ek = tid >> 5, chunk = tid & 31;
        int e = ek >> 1, k = ek & 1;
        int base = chunk * 128, c = cnt2[ek][chunk];
        for (int t = 0; t < 128; ++t) {
            int f = (base + t) * 2 + k;
            if (eidx[f] == e) { keepf[f] = (c < CAP) ? 1 : 0; ++c; }
        }
    }
    __syncthreads();
    {   // per-expert flat-order chunk counts (kept only)
        int e = tid >> 6, chunk = tid & 63;
        int base = chunk * 128, c = 0;
        for (int f = 0; f < 128; ++f) c += (eidx[base + f] == e && keepf[base + f]);
        cnt3[e][chunk] = c;
    }
    __syncthreads();
    if (tid < 16) {
        int s = 0;
        for (int c = 0; c < 64; ++c) { int v = cnt3[tid][c]; cnt3[tid][c] = s; s += v; }
        totals[tid] = s; counts[tid] = s;
    }
    __syncthreads();
    {   // assign slots
        int e = tid >> 6, chunk = tid & 63;
        int base = chunk * 128, c = cnt3[e][chunk];
        for (int f = 0; f < 128; ++f) {
            int fi = base + f;
            if (eidx[fi] == e && keepf[fi]) {
                disp[e * CBUF + c] = fi >> 1;
                wbuf[e * CBUF + c] = route_w[fi];
                ++c;
            }
        }
    }
    __syncthreads();
    for (int i = tid; i < NE * CBUF; i += 1024) {
        int e = i / CBUF, s = i % CBUF;
        if (s >= totals[e]) { disp[i] = T_TOK; wbuf[i] = 0.f; }
    }
}

// ---------------- GEMM1: xe @ {gate,up} fused + SiLU -> hidden (bf16) ----------------
__global__ __launch_bounds__(256, 2)
void gemm1_k(const unsigned short* __restrict__ xb, const unsigned short* __restrict__ gt,
             const unsigned short* __restrict__ ut, const int* __restrict__ disp,
             const int* __restrict__ counts, unsigned short* __restrict__ hidden) {
    int e = blockIdx.z, mt = blockIdx.y, nt = blockIdx.x;
    int m0 = mt * BM, n0 = nt * BN;
    if (m0 >= counts[e]) return;   // fully-padded tile: GEMM2 skips the same tiles
    __shared__ unsigned short As[BM * SAP];
    __shared__ unsigned short Bg[BN * SAP];
    __shared__ unsigned short Bu[BN * SAP];
    __shared__ int tok[BM];
    int tid = threadIdx.x;
    if (tid < BM) tok[tid] = disp[e * CBUF + m0 + tid];
    __syncthreads();
    int sr = tid >> 1, sc = (tid & 1) * 16;
    const unsigned short* abase = xb + (size_t)tok[sr] * DIM + sc;  // padding row -> zeros
    const unsigned short* gbase = gt + ((size_t)e * HID + n0 + sr) * DIM + sc;
    const unsigned short* ubase = ut + ((size_t)e * HID + n0 + sr) * DIM + sc;
    unsigned short* asw = As + sr * SAP + sc;
    unsigned short* bgw = Bg + sr * SAP + sc;
    unsigned short* buw = Bu + sr * SAP + sc;

    int lane = tid & 63, wv = tid >> 6;
    int wm = wv >> 1, wn = wv & 1;
    int quad = lane >> 4, ln = lane & 15;

    f32x4 zero4 = {0.f, 0.f, 0.f, 0.f};
    f32x4 accg[4][4], accu[4][4];
    #pragma unroll
    for (int i = 0; i < 4; ++i)
        #pragma unroll
        for (int j = 0; j < 4; ++j) { accg[i][j] = zero4; accu[i][j] = zero4; }

    for (int k0 = 0; k0 < DIM; k0 += BK) {
        uint4 a0 = *(const uint4*)(abase + k0);
        uint4 a1 = *(const uint4*)(abase + k0 + 8);
        uint4 g0 = *(const uint4*)(gbase + k0);
        uint4 g1 = *(const uint4*)(gbase + k0 + 8);
        uint4 u0 = *(const uint4*)(ubase + k0);
        uint4 u1 = *(const uint4*)(ubase + k0 + 8);
        *(uint4*)asw = a0; *(uint4*)(asw + 8) = a1;
        *(uint4*)bgw = g0; *(uint4*)(bgw + 8) = g1;
        *(uint4*)buw = u0; *(uint4*)(buw + 8) = u1;
        __syncthreads();
        short8 af[4], bgf[4], buf2[4];
        #pragma unroll
        for (int i = 0; i < 4; ++i)
            af[i] = *(const short8*)(As + (wm * 64 + i * 16 + ln) * SAP + quad * 8);
        #pragma unroll
        for (int j = 0; j < 4; ++j) {
            bgf[j]  = *(const short8*)(Bg + (wn * 64 + j * 16 + ln) * SAP + quad * 8);
            buf2[j] = *(const short8*)(Bu + (wn * 64 + j * 16 + ln) * SAP + quad * 8);
        }
        #pragma unroll
        for (int i = 0; i < 4; ++i)
            #pragma unroll
            for (int j = 0; j < 4; ++j) {
                accg[i][j] = __builtin_amdgcn_mfma_f32_16x16x32_bf16(af[i], bgf[j],  accg[i][j], 0, 0, 0);
                accu[i][j] = __builtin_amdgcn_mfma_f32_16x16x32_bf16(af[i], buf2[j], accu[i][j], 0, 0, 0);
            }
        __syncthreads();
    }
    // epilogue: hidden = silu(gate)*up, bf16
    #pragma unroll
    for (int i = 0; i < 4; ++i) {
        #pragma unroll
        for (int r = 0; r < 4; ++r) {
            int row = m0 + wm * 64 + i * 16 + quad * 4 + r;
            unsigned short* hrow = hidden + ((size_t)e * CBUF + row) * HID + n0 + wn * 64 + ln;
            #pragma unroll
            for (int j = 0; j < 4; ++j) {
                float g = accg[i][j][r];
                float u = accu[i][j][r];
                float sg = g / (1.f + __expf(-g));
                hrow[j * 16] = f2bf(sg * u);
            }
        }
    }
}

// ---------------- GEMM2: hidden @ down, scale by wbuf, scatter-add ----------------
__global__ __launch_bounds__(256, 2)
void gemm2_k(const unsigned short* __restrict__ hidden, const unsigned short* __restrict__ dt,
             const int* __restrict__ disp, const float* __restrict__ wb,
             const int* __restrict__ counts, float* __restrict__ out) {
    int e = blockIdx.z, mt = blockIdx.y, nt = blockIdx.x;
    int m0 = mt * BM, n0 = nt * BN;
    if (m0 >= counts[e]) return;
    __shared__ unsigned short As[BM * SAP];
    __shared__ unsigned short Bs[BN * SAP];
    __shared__ int tok[BM];
    __shared__ float twf[BM];
    int tid = threadIdx.x;
    if (tid < BM) {
        tok[tid] = disp[e * CBUF + m0 + tid];
        twf[tid] = wb[e * CBUF + m0 + tid];
    }
    __syncthreads();
    int sr = tid >> 1, sc = (tid & 1) * 16;
    const unsigned short* abase = hidden + ((size_t)e * CBUF + m0 + sr) * HID + sc;
    const unsigned short* bbase = dt + ((size_t)e * DIM + n0 + sr) * HID + sc;
    unsigned short* asw = As + sr * SAP + sc;
    unsigned short* bsw = Bs + sr * SAP + sc;

    int lane = tid & 63, wv = tid >> 6;
    int wm = wv >> 1, wn = wv & 1;
    int quad = lane >> 4, ln = lane & 15;

    f32x4 zero4 = {0.f, 0.f, 0.f, 0.f};
    f32x4 acc[4][4];
    #pragma unroll
    for (int i = 0; i < 4; ++i)
        #pragma unroll
        for (int j = 0; j < 4; ++j) acc[i][j] = zero4;

    for (int k0 = 0; k0 < HID; k0 += BK) {
        uint4 a0 = *(const uint4*)(abase + k0);
        uint4 a1 = *(const uint4*)(abase + k0 + 8);
        uint4 b0 = *(const uint4*)(bbase + k0);
        uint4 b1 = *(const uint4*)(bbase + k0 + 8);
        *(uint4*)asw = a0; *(uint4*)(asw + 8) = a1;
        *(uint4*)bsw = b0; *(uint4*)(bsw + 8) = b1;
        __syncthreads();
        short8 af[4], bf[4];
        #pragma unroll
        for (int i = 0; i < 4; ++i)
            af[i] = *(const short8*)(As + (wm * 64 + i * 16 + ln) * SAP + quad * 8);
        #pragma unroll
        for (int j = 0; j < 4; ++j)
            bf[j] = *(const short8*)(Bs + (wn * 64 + j * 16 + ln) * SAP + quad * 8);
        #pragma unroll
        for (int i = 0; i < 4; ++i)
            #pragma unroll
            for (int j = 0; j < 4; ++j)
                acc[i][j] = __builtin_amdgcn_mfma_f32_16x16x32_bf16(af[i], bf[j], acc[i][j], 0, 0, 0);
        __syncthreads();
    }
    #pragma unroll
    for (int i = 0; i < 4; ++i) {
        #pragma unroll
        for (int r = 0; r < 4; ++r) {
            int rl = wm * 64 + i * 16 + quad * 4 + r;
            int t = tok[rl];
            float w = twf[rl];
            if (t < T_TOK) {
                float* orow = out + (size_t)t * DIM + n0 + wn * 64 + ln;
                #pragma unroll
                for (int j = 0; j < 4; ++j)
                    atomicAdd(&orow[j * 16], acc[i][j][r] * w);
            }
        }
    }
}

extern "C" void kernel_launch(void* const* d_in, const int* in_sizes, int n_in,
                              void* d_out, int out_size, void* d_ws, size_t ws_size,
                              hipStream_t stream) {
    const float* x  = (const float*)d_in[0];   // (2,2048,1024)
    const float* rw = (const float*)d_in[1];   // (1024,16)
    const float* gw = (const float*)d_in[2];   // (16,1024,1024) [e][d][h]
    const float* uw = (const float*)d_in[3];   // (16,1024,1024) [e][d][h]
    const float* dw = (const float*)d_in[4];   // (16,1024,1024) [e][h][d]
    float* out = (float*)d_out;

    // workspace layout (~151 MB total)
    char* ws = (char*)d_ws;
    size_t off = 0;
    auto alloc = [&](size_t bytes) { void* p = ws + off; off += (bytes + 255) & ~(size_t)255; return p; };
    unsigned short* xb  = (unsigned short*)alloc((size_t)(T_TOK + 1) * DIM * 2);
    unsigned short* gt  = (unsigned short*)alloc((size_t)NE * DIM * HID * 2);  // [e][h][d]
    unsigned short* ut  = (unsigned short*)alloc((size_t)NE * DIM * HID * 2);  // [e][h][d]
    unsigned short* dtw = (unsigned short*)alloc((size_t)NE * DIM * HID * 2);  // [e][d][h]
    unsigned short* hid = (unsigned short*)alloc((size_t)NE * CBUF * HID * 2);
    int*   disp   = (int*)alloc((size_t)NE * CBUF * 4);
    float* wbf    = (float*)alloc((size_t)NE * CBUF * 4);
    int*   counts = (int*)alloc(64);
    int*   re     = (int*)alloc((size_t)T_TOK * 2 * 4);
    float* rwt    = (float*)alloc((size_t)T_TOK * 2 * 4);
    (void)ws_size; (void)in_sizes; (void)n_in;

    hipMemsetAsync(d_out, 0, (size_t)out_size * sizeof(float), stream);
    convert_x_k<<<T_TOK + 1, 256, 0, stream>>>(x, xb);
    dim3 tg(16, 16, 16);
    transpose_cvt_k<<<tg, 256, 0, stream>>>(gw, gt);
    transpose_cvt_k<<<tg, 256, 0, stream>>>(uw, ut);
    transpose_cvt_k<<<tg, 256, 0, stream>>>(dw, dtw);
    router_k<<<T_TOK, 64, 0, stream>>>(x, rw, re, rwt);
    build_dispatch_k<<<1, 1024, 0, stream>>>(re, rwt, disp, wbf, counts);
    gemm1_k<<<dim3(HID / BN, CBUF / BM, NE), 256, 0, stream>>>(xb, gt, ut, disp, counts, hid);
    gemm2_k<<<dim3(DIM / BN, CBUF / BM, NE), 256, 0, stream>>>(hid, dtw, disp, wbf, counts, out);
}

// Round 2
// 476.874 us; speedup vs baseline: 1.3820x; 1.3820x over previous
//
#include <hip/hip_runtime.h>
#include <math.h>

// Problem constants (B=2,S=2048 -> T=4096; D=H=1024; E=16; K=2; CF=1.25)
#define T_TOK 4096
#define DIM   1024
#define HID   1024
#define NE    16
#define CAP   640      // ceil(T*K/E*CF)
#define CBUF  1280     // K*CAP
#define BM 128
#define BN 128
#define BK 32
#define SAP 40         // LDS row stride in bf16 elems (32 + 8 pad -> 80B = 20 banks)

typedef __attribute__((ext_vector_type(8))) short short8;   // 8 bf16 (4 VGPRs)
typedef __attribute__((ext_vector_type(4))) float f32x4;    // MFMA accumulator

static __device__ __forceinline__ unsigned short f2bf(float f) {
    unsigned int u = __float_as_uint(f);
    u += 0x7fff + ((u >> 16) & 1);   // RNE
    return (unsigned short)(u >> 16);
}

// ---------------- x -> bf16 (with zero padding row at index T) ----------------
__global__ void convert_x_k(const float* __restrict__ x, unsigned short* __restrict__ xb) {
    int i = blockIdx.x * blockDim.x + threadIdx.x;  // group of 4 elems
    int base = i * 4;
    int row = base >> 10;
    ushort4 o;
    if (row < T_TOK) {
        float4 v = *(const float4*)(x + base);
        o.x = f2bf(v.x); o.y = f2bf(v.y); o.z = f2bf(v.z); o.w = f2bf(v.w);
    } else {
        o.x = 0; o.y = 0; o.z = 0; o.w = 0;
    }
    *(ushort4*)(xb + base) = o;
}

// ------------- weight fp32 [e][K][N] -> bf16 transposed [e][N][K] -------------
// K=N=1024 for all three tensors. 64x64 tiles via LDS.
__global__ void transpose_cvt_k(const float* __restrict__ W, unsigned short* __restrict__ Wt) {
    __shared__ unsigned short s[64][66];
    int e = blockIdx.z;
    const float* Wp = W + (size_t)e * DIM * HID;
    unsigned short* Wtp = Wt + (size_t)e * DIM * HID;
    int k0 = blockIdx.y * 64, n0 = blockIdx.x * 64;
    int tx = threadIdx.x & 15, ty = threadIdx.x >> 4;
    #pragma unroll
    for (int i = 0; i < 4; ++i) {
        int k = ty + i * 16;
        float4 v = *(const float4*)(Wp + (size_t)(k0 + k) * 1024 + n0 + tx * 4);
        s[k][tx*4+0] = f2bf(v.x); s[k][tx*4+1] = f2bf(v.y);
        s[k][tx*4+2] = f2bf(v.z); s[k][tx*4+3] = f2bf(v.w);
    }
    __syncthreads();
    #pragma unroll
    for (int i = 0; i < 4; ++i) {
        int n = ty + i * 16;
        ushort4 o;
        o.x = s[tx*4+0][n]; o.y = s[tx*4+1][n];
        o.z = s[tx*4+2][n]; o.w = s[tx*4+3][n];
        *(ushort4*)(Wtp + (size_t)(n0 + n) * 1024 + k0 + tx * 4) = o;
    }
}

// ---------------- router: logits, softmax, top-2 (one wave per token) ----------------
__global__ void router_k(const float* __restrict__ x, const float* __restrict__ rw,
                         int* __restrict__ route_e, float* __restrict__ route_w) {
    int t = blockIdx.x;
    int lane = threadIdx.x;
    const float* xr = x + (size_t)t * DIM + lane * 16;
    float4 xv0 = *(const float4*)(xr + 0);
    float4 xv1 = *(const float4*)(xr + 4);
    float4 xv2 = *(const float4*)(xr + 8);
    float4 xv3 = *(const float4*)(xr + 12);
    float xl[16] = {xv0.x, xv0.y, xv0.z, xv0.w, xv1.x, xv1.y, xv1.z, xv1.w,
                    xv2.x, xv2.y, xv2.z, xv2.w, xv3.x, xv3.y, xv3.z, xv3.w};
    float p[16];
    #pragma unroll
    for (int e = 0; e < 16; ++e) p[e] = 0.f;
    #pragma unroll
    for (int j = 0; j < 16; ++j) {
        const float4* rp = (const float4*)(rw + (size_t)(lane * 16 + j) * 16);
        float4 r0 = rp[0], r1 = rp[1], r2 = rp[2], r3 = rp[3];
        float xv = xl[j];
        p[0]  += xv * r0.x; p[1]  += xv * r0.y; p[2]  += xv * r0.z; p[3]  += xv * r0.w;
        p[4]  += xv * r1.x; p[5]  += xv * r1.y; p[6]  += xv * r1.z; p[7]  += xv * r1.w;
        p[8]  += xv * r2.x; p[9]  += xv * r2.y; p[10] += xv * r2.z; p[11] += xv * r2.w;
        p[12] += xv * r3.x; p[13] += xv * r3.y; p[14] += xv * r3.z; p[15] += xv * r3.w;
    }
    #pragma unroll
    for (int off = 32; off > 0; off >>= 1) {
        #pragma unroll
        for (int e = 0; e < 16; ++e) p[e] += __shfl_xor(p[e], off);
    }
    if (lane == 0) {
        float m = p[0];
        #pragma unroll
        for (int e = 1; e < 16; ++e) m = fmaxf(m, p[e]);
        float s = 0.f;
        #pragma unroll
        for (int e = 0; e < 16; ++e) s = s + __expf(p[e] - m);
        float v0 = -1e30f, v1 = -1e30f; int i0 = 0, i1 = 0;
        #pragma unroll
        for (int e = 0; e < 16; ++e) {
            float v = p[e];
            if (v > v0)      { v1 = v0; i1 = i0; v0 = v; i0 = e; }
            else if (v > v1) { v1 = v;  i1 = e; }
        }
        route_e[t*2+0] = i0;  route_e[t*2+1] = i1;
        route_w[t*2+0] = __expf(v0 - m) / s;
        route_w[t*2+1] = __expf(v1 - m) / s;
    }
}

// ------- dispatch build: ballot-based rank (per (e,k) stream) + slot (per-e flat stream) -------
// Replaces the chunked-scan version whose lane-strided LDS reads caused 521k
// bank-conflict cycles (~217 µs). Lanes now read consecutive bytes (<=4-way
// aliasing, ~free per m136); cumsums become ballot+popc with a scalar carry.
__global__ __launch_bounds__(1024)
void build_dispatch_k(const int* __restrict__ route_e, const float* __restrict__ route_w,
                      int* __restrict__ disp, float* __restrict__ wbuf, int* __restrict__ counts) {
    __shared__ unsigned char eidx[2 * T_TOK];    // expert id per flat entry
    __shared__ unsigned char keepf[2 * T_TOK];   // keep flag per flat entry
    __shared__ int totals[NE];
    int tid = threadIdx.x;
    int wv = tid >> 6, lane = tid & 63;

    // load route_e (8192 ints) -> bytes, coalesced; each thread packs 8 entries
    {
        int4 a = ((const int4*)route_e)[tid * 2];
        int4 b = ((const int4*)route_e)[tid * 2 + 1];
        unsigned int lo = (a.x & 0xff) | ((a.y & 0xff) << 8) | ((a.z & 0xff) << 16) | ((a.w & 0xff) << 24);
        unsigned int hi = (b.x & 0xff) | ((b.y & 0xff) << 8) | ((b.z & 0xff) << 16) | ((b.w & 0xff) << 24);
        uint2 pk; pk.x = lo; pk.y = hi;
        *(uint2*)(eidx + tid * 8) = pk;
    }
    __syncthreads();

    // Phase 1: keep = (token-order rank within (e,k) stream) < CAP.
    // 32 streams on 16 waves: each wave does streams wv and wv+16.
    unsigned long long below = (lane == 0) ? 0ull : ((~0ull) >> (64 - lane));
    #pragma unroll
    for (int s = 0; s < 2; ++s) {
        int st = wv + s * 16;
        int e = st >> 1, k = st & 1;
        int run = 0;
        for (int base = 0; base < T_TOK; base += 64) {
            int t = base + lane;
            int hit = (eidx[t * 2 + k] == e);
            unsigned long long m = __ballot(hit);
            int rank = run + __popcll(m & below);
            if (hit) keepf[t * 2 + k] = (rank < CAP) ? 1 : 0;
            run += __popcll(m);
        }
    }
    __syncthreads();

    // Phase 2: slot = flat-order rank among kept entries of expert e. One wave per expert.
    {
        int e = wv;
        int run = 0;
        for (int base = 0; base < 2 * T_TOK; base += 64) {
            int f = base + lane;
            int hit = (eidx[f] == e) && keepf[f];
            unsigned long long m = __ballot(hit);
            int slot = run + __popcll(m & below);
            if (hit) {
                disp[e * CBUF + slot] = f >> 1;
                wbuf[e * CBUF + slot] = route_w[f];
            }
            run += __popcll(m);
        }
        if (lane == 0) { counts[e] = run; totals[e] = run; }
    }
    __syncthreads();

    // Phase 3: pad unfilled slots (token index T -> zero row, weight 0)
    for (int i = tid; i < NE * CBUF; i += 1024) {
        int e = i / CBUF, s = i - e * CBUF;
        if (s >= totals[e]) { disp[i] = T_TOK; wbuf[i] = 0.f; }
    }
}

// ---------------- GEMM1: xe @ {gate,up} fused + SiLU -> hidden (bf16) ----------------
__global__ __launch_bounds__(256, 2)
void gemm1_k(const unsigned short* __restrict__ xb, const unsigned short* __restrict__ gt,
             const unsigned short* __restrict__ ut, const int* __restrict__ disp,
             const int* __restrict__ counts, unsigned short* __restrict__ hidden) {
    int e = blockIdx.z, mt = blockIdx.y, nt = blockIdx.x;
    int m0 = mt * BM, n0 = nt * BN;
    if (m0 >= counts[e]) return;   // fully-padded tile: GEMM2 skips the same tiles
    __shared__ unsigned short As[BM * SAP];
    __shared__ unsigned short Bg[BN * SAP];
    __shared__ unsigned short Bu[BN * SAP];
    __shared__ int tok[BM];
    int tid = threadIdx.x;
    if (tid < BM) tok[tid] = disp[e * CBUF + m0 + tid];
    __syncthreads();
    int sr = tid >> 1, sc = (tid & 1) * 16;
    const unsigned short* abase = xb + (size_t)tok[sr] * DIM + sc;  // padding row -> zeros
    const unsigned short* gbase = gt + ((size_t)e * HID + n0 + sr) * DIM + sc;
    const unsigned short* ubase = ut + ((size_t)e * HID + n0 + sr) * DIM + sc;
    unsigned short* asw = As + sr * SAP + sc;
    unsigned short* bgw = Bg + sr * SAP + sc;
    unsigned short* buw = Bu + sr * SAP + sc;

    int lane = tid & 63, wv = tid >> 6;
    int wm = wv >> 1, wn = wv & 1;
    int quad = lane >> 4, ln = lane & 15;

    f32x4 zero4 = {0.f, 0.f, 0.f, 0.f};
    f32x4 accg[4][4], accu[4][4];
    #pragma unroll
    for (int i = 0; i < 4; ++i)
        #pragma unroll
        for (int j = 0; j < 4; ++j) { accg[i][j] = zero4; accu[i][j] = zero4; }

    for (int k0 = 0; k0 < DIM; k0 += BK) {
        uint4 a0 = *(const uint4*)(abase + k0);
        uint4 a1 = *(const uint4*)(abase + k0 + 8);
        uint4 g0 = *(const uint4*)(gbase + k0);
        uint4 g1 = *(const uint4*)(gbase + k0 + 8);
        uint4 u0 = *(const uint4*)(ubase + k0);
        uint4 u1 = *(const uint4*)(ubase + k0 + 8);
        *(uint4*)asw = a0; *(uint4*)(asw + 8) = a1;
        *(uint4*)bgw = g0; *(uint4*)(bgw + 8) = g1;
        *(uint4*)buw = u0; *(uint4*)(buw + 8) = u1;
        __syncthreads();
        short8 af[4], bgf[4], buf2[4];
        #pragma unroll
        for (int i = 0; i < 4; ++i)
            af[i] = *(const short8*)(As + (wm * 64 + i * 16 + ln) * SAP + quad * 8);
        #pragma unroll
        for (int j = 0; j < 4; ++j) {
            bgf[j]  = *(const short8*)(Bg + (wn * 64 + j * 16 + ln) * SAP + quad * 8);
            buf2[j] = *(const short8*)(Bu + (wn * 64 + j * 16 + ln) * SAP + quad * 8);
        }
        #pragma unroll
        for (int i = 0; i < 4; ++i)
            #pragma unroll
            for (int j = 0; j < 4; ++j) {
                accg[i][j] = __builtin_amdgcn_mfma_f32_16x16x32_bf16(af[i], bgf[j],  accg[i][j], 0, 0, 0);
                accu[i][j] = __builtin_amdgcn_mfma_f32_16x16x32_bf16(af[i], buf2[j], accu[i][j], 0, 0, 0);
            }
        __syncthreads();
    }
    // epilogue: hidden = silu(gate)*up, bf16
    #pragma unroll
    for (int i = 0; i < 4; ++i) {
        #pragma unroll
        for (int r = 0; r < 4; ++r) {
            int row = m0 + wm * 64 + i * 16 + quad * 4 + r;
            unsigned short* hrow = hidden + ((size_t)e * CBUF + row) * HID + n0 + wn * 64 + ln;
            #pragma unroll
            for (int j = 0; j < 4; ++j) {
                float g = accg[i][j][r];
                float u = accu[i][j][r];
                float sg = g / (1.f + __expf(-g));
                hrow[j * 16] = f2bf(sg * u);
            }
        }
    }
}

// ---------------- GEMM2: hidden @ down, scale by wbuf, scatter-add ----------------
__global__ __launch_bounds__(256, 2)
void gemm2_k(const unsigned short* __restrict__ hidden, const unsigned short* __restrict__ dt,
             const int* __restrict__ disp, const float* __restrict__ wb,
             const int* __restrict__ counts, float* __restrict__ out) {
    int e = blockIdx.z, mt = blockIdx.y, nt = blockIdx.x;
    int m0 = mt * BM, n0 = nt * BN;
    if (m0 >= counts[e]) return;
    __shared__ unsigned short As[BM * SAP];
    __shared__ unsigned short Bs[BN * SAP];
    __shared__ int tok[BM];
    __shared__ float twf[BM];
    int tid = threadIdx.x;
    if (tid < BM) {
        tok[tid] = disp[e * CBUF + m0 + tid];
        twf[tid] = wb[e * CBUF + m0 + tid];
    }
    __syncthreads();
    int sr = tid >> 1, sc = (tid & 1) * 16;
    const unsigned short* abase = hidden + ((size_t)e * CBUF + m0 + sr) * HID + sc;
    const unsigned short* bbase = dt + ((size_t)e * DIM + n0 + sr) * HID + sc;
    unsigned short* asw = As + sr * SAP + sc;
    unsigned short* bsw = Bs + sr * SAP + sc;

    int lane = tid & 63, wv = tid >> 6;
    int wm = wv >> 1, wn = wv & 1;
    int quad = lane >> 4, ln = lane & 15;

    f32x4 zero4 = {0.f, 0.f, 0.f, 0.f};
    f32x4 acc[4][4];
    #pragma unroll
    for (int i = 0; i < 4; ++i)
        #pragma unroll
        for (int j = 0; j < 4; ++j) acc[i][j] = zero4;

    for (int k0 = 0; k0 < HID; k0 += BK) {
        uint4 a0 = *(const uint4*)(abase + k0);
        uint4 a1 = *(const uint4*)(abase + k0 + 8);
        uint4 b0 = *(const uint4*)(bbase + k0);
        uint4 b1 = *(const uint4*)(bbase + k0 + 8);
        *(uint4*)asw = a0; *(uint4*)(asw + 8) = a1;
        *(uint4*)bsw = b0; *(uint4*)(bsw + 8) = b1;
        __syncthreads();
        short8 af[4], bf[4];
        #pragma unroll
        for (int i = 0; i < 4; ++i)
            af[i] = *(const short8*)(As + (wm * 64 + i * 16 + ln) * SAP + quad * 8);
        #pragma unroll
        for (int j = 0; j < 4; ++j)
            bf[j] = *(const short8*)(Bs + (wn * 64 + j * 16 + ln) * SAP + quad * 8);
        #pragma unroll
        for (int i = 0; i < 4; ++i)
            #pragma unroll
            for (int j = 0; j < 4; ++j)
                acc[i][j] = __builtin_amdgcn_mfma_f32_16x16x32_bf16(af[i], bf[j], acc[i][j], 0, 0, 0);
        __syncthreads();
    }
    #pragma unroll
    for (int i = 0; i < 4; ++i) {
        #pragma unroll
        for (int r = 0; r < 4; ++r) {
            int rl = wm * 64 + i * 16 + quad * 4 + r;
            int t = tok[rl];
            float w = twf[rl];
            if (t < T_TOK) {
                float* orow = out + (size_t)t * DIM + n0 + wn * 64 + ln;
                #pragma unroll
                for (int j = 0; j < 4; ++j)
                    atomicAdd(&orow[j * 16], acc[i][j][r] * w);
            }
        }
    }
}

extern "C" void kernel_launch(void* const* d_in, const int* in_sizes, int n_in,
                              void* d_out, int out_size, void* d_ws, size_t ws_size,
                              hipStream_t stream) {
    const float* x  = (const float*)d_in[0];   // (2,2048,1024)
    const float* rw = (const float*)d_in[1];   // (1024,16)
    const float* gw = (const float*)d_in[2];   // (16,1024,1024) [e][d][h]
    const float* uw = (const float*)d_in[3];   // (16,1024,1024) [e][d][h]
    const float* dw = (const float*)d_in[4];   // (16,1024,1024) [e][h][d]
    float* out = (float*)d_out;

    // workspace layout (~151 MB total)
    char* ws = (char*)d_ws;
    size_t off = 0;
    auto alloc = [&](size_t bytes) { void* p = ws + off; off += (bytes + 255) & ~(size_t)255; return p; };
    unsigned short* xb  = (unsigned short*)alloc((size_t)(T_TOK + 1) * DIM * 2);
    unsigned short* gt  = (unsigned short*)alloc((size_t)NE * DIM * HID * 2);  // [e][h][d]
    unsigned short* ut  = (unsigned short*)alloc((size_t)NE * DIM * HID * 2);  // [e][h][d]
    unsigned short* dtw = (unsigned short*)alloc((size_t)NE * DIM * HID * 2);  // [e][d][h]
    unsigned short* hid = (unsigned short*)alloc((size_t)NE * CBUF * HID * 2);
    int*   disp   = (int*)alloc((size_t)NE * CBUF * 4);
    float* wbf    = (float*)alloc((size_t)NE * CBUF * 4);
    int*   counts = (int*)alloc(64);
    int*   re     = (int*)alloc((size_t)T_TOK * 2 * 4);
    float* rwt    = (float*)alloc((size_t)T_TOK * 2 * 4);
    (void)ws_size; (void)in_sizes; (void)n_in;

    hipMemsetAsync(d_out, 0, (size_t)out_size * sizeof(float), stream);
    convert_x_k<<<T_TOK + 1, 256, 0, stream>>>(x, xb);
    dim3 tg(16, 16, 16);
    transpose_cvt_k<<<tg, 256, 0, stream>>>(gw, gt);
    transpose_cvt_k<<<tg, 256, 0, stream>>>(uw, ut);
    transpose_cvt_k<<<tg, 256, 0, stream>>>(dw, dtw);
    router_k<<<T_TOK, 64, 0, stream>>>(x, rw, re, rwt);
    build_dispatch_k<<<1, 1024, 0, stream>>>(re, rwt, disp, wbf, counts);
    gemm1_k<<<dim3(HID / BN, CBUF / BM, NE), 256, 0, stream>>>(xb, gt, ut, disp, counts, hid);
    gemm2_k<<<dim3(DIM / BN, CBUF / BM, NE), 256, 0, stream>>>(hid, dtw, disp, wbf, counts, out);
}

// Round 3
// 444.859 us; speedup vs baseline: 1.4815x; 1.0720x over previous
//
#include <hip/hip_runtime.h>
#include <math.h>

// Problem constants (B=2,S=2048 -> T=4096; D=H=1024; E=16; K=2; CF=1.25)
#define T_TOK 4096
#define DIM   1024
#define HID   1024
#define NE    16
#define CAP   640      // ceil(T*K/E*CF)
#define CBUF  1280     // K*CAP
#define BM 128
#define BN 128
#define BK 32
#define MAXTILE 160    // NE * (CBUF/BM) upper bound on active m-tiles

typedef __attribute__((ext_vector_type(8))) short short8;   // 8 bf16 (4 VGPRs)
typedef __attribute__((ext_vector_type(4))) float f32x4;    // MFMA accumulator

static __device__ __forceinline__ unsigned short f2bf(float f) {
    unsigned int u = __float_as_uint(f);
    u += 0x7fff + ((u >> 16) & 1);   // RNE
    return (unsigned short)(u >> 16);
}

// async global->LDS DMA, 16B per lane. dst must be wave-uniform base; lane i
// lands at dst + i*16. We choose per-lane SOURCE chunks to realize an XOR
// swizzle in LDS (chunk c of row r stored at position c ^ ((r>>1)&3)) so the
// unpadded 64B-row layout reads conflict-free (2-way only) with ds_read_b128.
static __device__ __forceinline__ void async16(const void* g, void* l) {
    __builtin_amdgcn_global_load_lds((const __attribute__((address_space(1))) void*)g,
                                     (__attribute__((address_space(3))) void*)l, 16, 0, 0);
}

// ---------------- x -> bf16 (with zero padding row at index T) ----------------
__global__ void convert_x_k(const float* __restrict__ x, unsigned short* __restrict__ xb) {
    int i = blockIdx.x * blockDim.x + threadIdx.x;  // group of 4 elems
    int base = i * 4;
    int row = base >> 10;
    ushort4 o;
    if (row < T_TOK) {
        float4 v = *(const float4*)(x + base);
        o.x = f2bf(v.x); o.y = f2bf(v.y); o.z = f2bf(v.z); o.w = f2bf(v.w);
    } else {
        o.x = 0; o.y = 0; o.z = 0; o.w = 0;
    }
    *(ushort4*)(xb + base) = o;
}

// ------------- fused weight transpose: fp32 [e][k][n] -> bf16 [e][n][k] -------------
// All three weight tensors in one launch (blockIdx.z selects tensor+expert).
// 64x64 tiles; vectorized global I/O; LDS stride 68 (writes ~4-way, reads ~2-way).
#define TSP 68
__global__ void transpose_cvt_k(const float* __restrict__ W0, const float* __restrict__ W1,
                                const float* __restrict__ W2,
                                unsigned short* __restrict__ T0, unsigned short* __restrict__ T1,
                                unsigned short* __restrict__ T2) {
    __shared__ unsigned short s[64 * TSP];
    int zz = blockIdx.z;                 // 0..47
    int which = zz >> 4, e = zz & 15;
    const float* W = (which == 0) ? W0 : (which == 1) ? W1 : W2;
    unsigned short* T = (which == 0) ? T0 : (which == 1) ? T1 : T2;
    const float* Wp = W + (size_t)e * DIM * HID;
    unsigned short* Tp = T + (size_t)e * DIM * HID;
    int k0 = blockIdx.y * 64, n0 = blockIdx.x * 64;
    int tid = threadIdx.x;
    int tx = tid & 15, ty = tid >> 4;    // ty 0..15
    #pragma unroll
    for (int i = 0; i < 4; ++i) {
        int k = ty + i * 16;
        float4 v = *(const float4*)(Wp + (size_t)(k0 + k) * 1024 + n0 + tx * 4);
        int nb = tx * 4;
        s[(nb + 0) * TSP + k] = f2bf(v.x);
        s[(nb + 1) * TSP + k] = f2bf(v.y);
        s[(nb + 2) * TSP + k] = f2bf(v.z);
        s[(nb + 3) * TSP + k] = f2bf(v.w);
    }
    __syncthreads();
    int n = tid >> 2, cseg = (tid & 3) * 16;     // row n, 16-col segment
    union { ushort4 h[4]; uint4 q[2]; } u;
    #pragma unroll
    for (int j = 0; j < 4; ++j)
        u.h[j] = *(ushort4*)&s[n * TSP + cseg + 4 * j];
    unsigned short* orow = Tp + (size_t)(n0 + n) * 1024 + k0 + cseg;
    *(uint4*)(orow + 0) = u.q[0];
    *(uint4*)(orow + 8) = u.q[1];
}

// ---------------- router: logits, softmax, top-2 (one wave per token) ----------------
__global__ void router_k(const float* __restrict__ x, const float* __restrict__ rw,
                         int* __restrict__ route_e, float* __restrict__ route_w) {
    int t = blockIdx.x;
    int lane = threadIdx.x;
    const float* xr = x + (size_t)t * DIM + lane * 16;
    float4 xv0 = *(const float4*)(xr + 0);
    float4 xv1 = *(const float4*)(xr + 4);
    float4 xv2 = *(const float4*)(xr + 8);
    float4 xv3 = *(const float4*)(xr + 12);
    float xl[16] = {xv0.x, xv0.y, xv0.z, xv0.w, xv1.x, xv1.y, xv1.z, xv1.w,
                    xv2.x, xv2.y, xv2.z, xv2.w, xv3.x, xv3.y, xv3.z, xv3.w};
    float p[16];
    #pragma unroll
    for (int e = 0; e < 16; ++e) p[e] = 0.f;
    #pragma unroll
    for (int j = 0; j < 16; ++j) {
        const float4* rp = (const float4*)(rw + (size_t)(lane * 16 + j) * 16);
        float4 r0 = rp[0], r1 = rp[1], r2 = rp[2], r3 = rp[3];
        float xv = xl[j];
        p[0]  += xv * r0.x; p[1]  += xv * r0.y; p[2]  += xv * r0.z; p[3]  += xv * r0.w;
        p[4]  += xv * r1.x; p[5]  += xv * r1.y; p[6]  += xv * r1.z; p[7]  += xv * r1.w;
        p[8]  += xv * r2.x; p[9]  += xv * r2.y; p[10] += xv * r2.z; p[11] += xv * r2.w;
        p[12] += xv * r3.x; p[13] += xv * r3.y; p[14] += xv * r3.z; p[15] += xv * r3.w;
    }
    #pragma unroll
    for (int off = 32; off > 0; off >>= 1) {
        #pragma unroll
        for (int e = 0; e < 16; ++e) p[e] += __shfl_xor(p[e], off);
    }
    if (lane == 0) {
        float m = p[0];
        #pragma unroll
        for (int e = 1; e < 16; ++e) m = fmaxf(m, p[e]);
        float s = 0.f;
        #pragma unroll
        for (int e = 0; e < 16; ++e) s = s + __expf(p[e] - m);
        float v0 = -1e30f, v1 = -1e30f; int i0 = 0, i1 = 0;
        #pragma unroll
        for (int e = 0; e < 16; ++e) {
            float v = p[e];
            if (v > v0)      { v1 = v0; i1 = i0; v0 = v; i0 = e; }
            else if (v > v1) { v1 = v;  i1 = e; }
        }
        route_e[t*2+0] = i0;  route_e[t*2+1] = i1;
        route_w[t*2+0] = __expf(v0 - m) / s;
        route_w[t*2+1] = __expf(v1 - m) / s;
    }
}

// ------- dispatch build: ballot-based rank/slot + active-tile list -------
__global__ __launch_bounds__(1024)
void build_dispatch_k(const int* __restrict__ route_e, const float* __restrict__ route_w,
                      int* __restrict__ disp, float* __restrict__ wbuf, int* __restrict__ tmeta) {
    __shared__ unsigned char eidx[2 * T_TOK];
    __shared__ unsigned char keepf[2 * T_TOK];
    __shared__ int totals[NE];
    int tid = threadIdx.x;
    int wv = tid >> 6, lane = tid & 63;

    {   // route_e (8192 ints) -> bytes, coalesced
        int4 a = ((const int4*)route_e)[tid * 2];
        int4 b = ((const int4*)route_e)[tid * 2 + 1];
        unsigned int lo = (a.x & 0xff) | ((a.y & 0xff) << 8) | ((a.z & 0xff) << 16) | ((a.w & 0xff) << 24);
        unsigned int hi = (b.x & 0xff) | ((b.y & 0xff) << 8) | ((b.z & 0xff) << 16) | ((b.w & 0xff) << 24);
        uint2 pk; pk.x = lo; pk.y = hi;
        *(uint2*)(eidx + tid * 8) = pk;
    }
    __syncthreads();

    unsigned long long below = (lane == 0) ? 0ull : ((~0ull) >> (64 - lane));
    #pragma unroll
    for (int s = 0; s < 2; ++s) {      // keep = token-order rank in (e,k) stream < CAP
        int st = wv + s * 16;
        int e = st >> 1, k = st & 1;
        int run = 0;
        for (int base = 0; base < T_TOK; base += 64) {
            int t = base + lane;
            int hit = (eidx[t * 2 + k] == e);
            unsigned long long m = __ballot(hit);
            int rank = run + __popcll(m & below);
            if (hit) keepf[t * 2 + k] = (rank < CAP) ? 1 : 0;
            run += __popcll(m);
        }
    }
    __syncthreads();

    {   // slot = flat-order rank among kept entries of expert e (one wave per expert)
        int e = wv;
        int run = 0;
        for (int base = 0; base < 2 * T_TOK; base += 64) {
            int f = base + lane;
            int hit = (eidx[f] == e) && keepf[f];
            unsigned long long m = __ballot(hit);
            int slot = run + __popcll(m & below);
            if (hit) {
                disp[e * CBUF + slot] = f >> 1;
                wbuf[e * CBUF + slot] = route_w[f];
            }
            run += __popcll(m);
        }
        if (lane == 0) totals[e] = run;
    }
    __syncthreads();

    // pad unfilled slots (token index T -> zero row, weight 0)
    for (int i = tid; i < NE * CBUF; i += 1024) {
        int e = i / CBUF, s = i - e * CBUF;
        if (s >= totals[e]) { disp[i] = T_TOK; wbuf[i] = 0.f; }
    }

    // active-tile list: tmeta[0]=n_tiles, tmeta[4+i] = (e<<8)|mt
    if (tid == 0) {
        int n = 0;
        for (int e = 0; e < NE; ++e) {
            int ntl = (totals[e] + BM - 1) / BM;
            for (int m = 0; m < ntl; ++m) { tmeta[4 + n] = (e << 8) | m; ++n; }
        }
        tmeta[0] = n;
    }
}

// ---------------- GEMM1: xe @ {gate,up} fused + SiLU -> hidden (bf16) ----------------
// global_load_lds(16B) staging, XOR-swizzled unpadded LDS, tile-list scheduling.
__global__ __launch_bounds__(256, 2)
void gemm1_k(const unsigned short* __restrict__ xb, const unsigned short* __restrict__ gt,
             const unsigned short* __restrict__ ut, const int* __restrict__ disp,
             const int* __restrict__ tmeta, unsigned short* __restrict__ hidden) {
    int slot = blockIdx.y;
    if (slot >= tmeta[0]) return;
    int pk = tmeta[4 + slot];
    int e = pk >> 8, mt = pk & 255;
    int m0 = mt * BM, n0 = blockIdx.x * BN;

    __shared__ unsigned short As[BM * BK];
    __shared__ unsigned short Bg[BN * BK];
    __shared__ unsigned short Bu[BN * BK];
    __shared__ int tok[BM];
    int tid = threadIdx.x;
    if (tid < BM) tok[tid] = disp[e * CBUF + m0 + tid];
    __syncthreads();

    int lane = tid & 63, w = tid >> 6;
    int cg = (lane & 3) ^ ((lane >> 3) & 3);   // swizzled source chunk index
    int rl = lane >> 2;                         // local row in 16-row group
    int rA0 = w * 32 + rl, rA1 = rA0 + 16;
    const unsigned short* srcA0 = xb + (size_t)tok[rA0] * DIM + cg * 8;
    const unsigned short* srcA1 = xb + (size_t)tok[rA1] * DIM + cg * 8;
    const unsigned short* srcG0 = gt + ((size_t)e * HID + n0 + rA0) * DIM + cg * 8;
    const unsigned short* srcG1 = gt + ((size_t)e * HID + n0 + rA1) * DIM + cg * 8;
    const unsigned short* srcU0 = ut + ((size_t)e * HID + n0 + rA0) * DIM + cg * 8;
    const unsigned short* srcU1 = ut + ((size_t)e * HID + n0 + rA1) * DIM + cg * 8;
    unsigned short* dA0 = As + (size_t)(w * 32) * BK;
    unsigned short* dA1 = As + (size_t)(w * 32 + 16) * BK;
    unsigned short* dG0 = Bg + (size_t)(w * 32) * BK;
    unsigned short* dG1 = Bg + (size_t)(w * 32 + 16) * BK;
    unsigned short* dU0 = Bu + (size_t)(w * 32) * BK;
    unsigned short* dU1 = Bu + (size_t)(w * 32 + 16) * BK;

    int wm = w >> 1, wn = w & 1;
    int quad = lane >> 4, ln = lane & 15;
    int swq = quad ^ ((ln >> 1) & 3);          // read-side swizzle (row bits reduce to ln)

    f32x4 zero4 = {0.f, 0.f, 0.f, 0.f};
    f32x4 accg[4][4], accu[4][4];
    #pragma unroll
    for (int i = 0; i < 4; ++i)
        #pragma unroll
        for (int j = 0; j < 4; ++j) { accg[i][j] = zero4; accu[i][j] = zero4; }

    for (int k0 = 0; k0 < DIM; k0 += BK) {
        async16(srcA0, dA0); async16(srcA1, dA1);
        async16(srcG0, dG0); async16(srcG1, dG1);
        async16(srcU0, dU0); async16(srcU1, dU1);
        srcA0 += BK; srcA1 += BK; srcG0 += BK; srcG1 += BK; srcU0 += BK; srcU1 += BK;
        asm volatile("s_waitcnt vmcnt(0)" ::: "memory");
        __syncthreads();
        short8 af[4], bgf[4], buf2[4];
        #pragma unroll
        for (int i = 0; i < 4; ++i)
            af[i] = *(const short8*)(As + (wm * 64 + i * 16 + ln) * BK + swq * 8);
        #pragma unroll
        for (int j = 0; j < 4; ++j) {
            bgf[j]  = *(const short8*)(Bg + (wn * 64 + j * 16 + ln) * BK + swq * 8);
            buf2[j] = *(const short8*)(Bu + (wn * 64 + j * 16 + ln) * BK + swq * 8);
        }
        #pragma unroll
        for (int i = 0; i < 4; ++i)
            #pragma unroll
            for (int j = 0; j < 4; ++j) {
                accg[i][j] = __builtin_amdgcn_mfma_f32_16x16x32_bf16(af[i], bgf[j],  accg[i][j], 0, 0, 0);
                accu[i][j] = __builtin_amdgcn_mfma_f32_16x16x32_bf16(af[i], buf2[j], accu[i][j], 0, 0, 0);
            }
        __syncthreads();
    }
    #pragma unroll
    for (int i = 0; i < 4; ++i) {
        #pragma unroll
        for (int r = 0; r < 4; ++r) {
            int row = m0 + wm * 64 + i * 16 + quad * 4 + r;
            unsigned short* hrow = hidden + ((size_t)e * CBUF + row) * HID + n0 + wn * 64 + ln;
            #pragma unroll
            for (int j = 0; j < 4; ++j) {
                float g = accg[i][j][r];
                float u = accu[i][j][r];
                float sg = g / (1.f + __expf(-g));
                hrow[j * 16] = f2bf(sg * u);
            }
        }
    }
}

// ---------------- GEMM2: hidden @ down, scale by wbuf, scatter-add ----------------
__global__ __launch_bounds__(256, 2)
void gemm2_k(const unsigned short* __restrict__ hidden, const unsigned short* __restrict__ dt,
             const int* __restrict__ disp, const float* __restrict__ wb,
             const int* __restrict__ tmeta, float* __restrict__ out) {
    int slot = blockIdx.y;
    if (slot >= tmeta[0]) return;
    int pk = tmeta[4 + slot];
    int e = pk >> 8, mt = pk & 255;
    int m0 = mt * BM, n0 = blockIdx.x * BN;

    __shared__ unsigned short As[BM * BK];
    __shared__ unsigned short Bs[BN * BK];
    __shared__ int tok[BM];
    __shared__ float twf[BM];
    int tid = threadIdx.x;
    if (tid < BM) {
        tok[tid] = disp[e * CBUF + m0 + tid];
        twf[tid] = wb[e * CBUF + m0 + tid];
    }
    __syncthreads();

    int lane = tid & 63, w = tid >> 6;
    int cg = (lane & 3) ^ ((lane >> 3) & 3);
    int rl = lane >> 2;
    int rA0 = w * 32 + rl, rA1 = rA0 + 16;
    const unsigned short* srcA0 = hidden + ((size_t)e * CBUF + m0 + rA0) * HID + cg * 8;
    const unsigned short* srcA1 = hidden + ((size_t)e * CBUF + m0 + rA1) * HID + cg * 8;
    const unsigned short* srcB0 = dt + ((size_t)e * DIM + n0 + rA0) * HID + cg * 8;
    const unsigned short* srcB1 = dt + ((size_t)e * DIM + n0 + rA1) * HID + cg * 8;
    unsigned short* dA0 = As + (size_t)(w * 32) * BK;
    unsigned short* dA1 = As + (size_t)(w * 32 + 16) * BK;
    unsigned short* dB0 = Bs + (size_t)(w * 32) * BK;
    unsigned short* dB1 = Bs + (size_t)(w * 32 + 16) * BK;

    int wm = w >> 1, wn = w & 1;
    int quad = lane >> 4, ln = lane & 15;
    int swq = quad ^ ((ln >> 1) & 3);

    f32x4 zero4 = {0.f, 0.f, 0.f, 0.f};
    f32x4 acc[4][4];
    #pragma unroll
    for (int i = 0; i < 4; ++i)
        #pragma unroll
        for (int j = 0; j < 4; ++j) acc[i][j] = zero4;

    for (int k0 = 0; k0 < HID; k0 += BK) {
        async16(srcA0, dA0); async16(srcA1, dA1);
        async16(srcB0, dB0); async16(srcB1, dB1);
        srcA0 += BK; srcA1 += BK; srcB0 += BK; srcB1 += BK;
        asm volatile("s_waitcnt vmcnt(0)" ::: "memory");
        __syncthreads();
        short8 af[4], bf[4];
        #pragma unroll
        for (int i = 0; i < 4; ++i)
            af[i] = *(const short8*)(As + (wm * 64 + i * 16 + ln) * BK + swq * 8);
        #pragma unroll
        for (int j = 0; j < 4; ++j)
            bf[j] = *(const short8*)(Bs + (wn * 64 + j * 16 + ln) * BK + swq * 8);
        #pragma unroll
        for (int i = 0; i < 4; ++i)
            #pragma unroll
            for (int j = 0; j < 4; ++j)
                acc[i][j] = __builtin_amdgcn_mfma_f32_16x16x32_bf16(af[i], bf[j], acc[i][j], 0, 0, 0);
        __syncthreads();
    }
    #pragma unroll
    for (int i = 0; i < 4; ++i) {
        #pragma unroll
        for (int r = 0; r < 4; ++r) {
            int rl2 = wm * 64 + i * 16 + quad * 4 + r;
            int t = tok[rl2];
            float wgt = twf[rl2];
            if (t < T_TOK) {
                float* orow = out + (size_t)t * DIM + n0 + wn * 64 + ln;
                #pragma unroll
                for (int j = 0; j < 4; ++j)
                    atomicAdd(&orow[j * 16], acc[i][j][r] * wgt);
            }
        }
    }
}

extern "C" void kernel_launch(void* const* d_in, const int* in_sizes, int n_in,
                              void* d_out, int out_size, void* d_ws, size_t ws_size,
                              hipStream_t stream) {
    const float* x  = (const float*)d_in[0];   // (2,2048,1024)
    const float* rw = (const float*)d_in[1];   // (1024,16)
    const float* gw = (const float*)d_in[2];   // (16,1024,1024) [e][d][h]
    const float* uw = (const float*)d_in[3];   // (16,1024,1024) [e][d][h]
    const float* dw = (const float*)d_in[4];   // (16,1024,1024) [e][h][d]
    float* out = (float*)d_out;

    char* ws = (char*)d_ws;
    size_t off = 0;
    auto alloc = [&](size_t bytes) { void* p = ws + off; off += (bytes + 255) & ~(size_t)255; return p; };
    unsigned short* xb  = (unsigned short*)alloc((size_t)(T_TOK + 1) * DIM * 2);
    unsigned short* gt  = (unsigned short*)alloc((size_t)NE * DIM * HID * 2);  // [e][h][d]
    unsigned short* ut  = (unsigned short*)alloc((size_t)NE * DIM * HID * 2);  // [e][h][d]
    unsigned short* dtw = (unsigned short*)alloc((size_t)NE * DIM * HID * 2);  // [e][d][h]
    unsigned short* hid = (unsigned short*)alloc((size_t)NE * CBUF * HID * 2);
    int*   disp   = (int*)alloc((size_t)NE * CBUF * 4);
    float* wbf    = (float*)alloc((size_t)NE * CBUF * 4);
    int*   tmeta  = (int*)alloc((4 + MAXTILE) * 4);
    int*   re     = (int*)alloc((size_t)T_TOK * 2 * 4);
    float* rwt    = (float*)alloc((size_t)T_TOK * 2 * 4);
    (void)ws_size; (void)in_sizes; (void)n_in;

    hipMemsetAsync(d_out, 0, (size_t)out_size * sizeof(float), stream);
    convert_x_k<<<T_TOK + 1, 256, 0, stream>>>(x, xb);
    transpose_cvt_k<<<dim3(16, 16, 48), 256, 0, stream>>>(gw, uw, dw, gt, ut, dtw);
    router_k<<<T_TOK, 64, 0, stream>>>(x, rw, re, rwt);
    build_dispatch_k<<<1, 1024, 0, stream>>>(re, rwt, disp, wbf, tmeta);
    gemm1_k<<<dim3(HID / BN, MAXTILE), 256, 0, stream>>>(xb, gt, ut, disp, tmeta, hid);
    gemm2_k<<<dim3(DIM / BN, MAXTILE), 256, 0, stream>>>(hid, dtw, disp, wbf, tmeta, out);
}

// Round 4
// 413.080 us; speedup vs baseline: 1.5955x; 1.0769x over previous
//
#include <hip/hip_runtime.h>
#include <math.h>

// Problem constants (B=2,S=2048 -> T=4096; D=H=1024; E=16; K=2; CF=1.25)
#define T_TOK 4096
#define DIM   1024
#define HID   1024
#define NE    16
#define CAP   640      // ceil(T*K/E*CF)
#define CBUF  1280     // K*CAP
#define BM 128
#define BN 128
#define BK 32
#define MAXTILE 160    // NE * (CBUF/BM) upper bound on active m-tiles

typedef __attribute__((ext_vector_type(8))) short short8;   // 8 bf16 (4 VGPRs)
typedef __attribute__((ext_vector_type(4))) float f32x4;    // MFMA accumulator

static __device__ __forceinline__ unsigned short f2bf(float f) {
    unsigned int u = __float_as_uint(f);
    u += 0x7fff + ((u >> 16) & 1);   // RNE
    return (unsigned short)(u >> 16);
}

// async global->LDS DMA, 16B per lane; dst is wave-uniform base, lane i lands
// at dst + i*16. Source chunks are XOR-swizzled (chunk c of row r at c^((r>>1)&3))
// so the unpadded 64B-row LDS layout reads conflict-free with ds_read_b128.
static __device__ __forceinline__ void async16(const void* g, void* l) {
    __builtin_amdgcn_global_load_lds((const __attribute__((address_space(1))) void*)g,
                                     (__attribute__((address_space(3))) void*)l, 16, 0, 0);
}

// ---------------- x -> bf16 (with zero padding row at index T) ----------------
__global__ void convert_x_k(const float* __restrict__ x, unsigned short* __restrict__ xb) {
    int i = blockIdx.x * blockDim.x + threadIdx.x;
    int base = i * 4;
    int row = base >> 10;
    ushort4 o;
    if (row < T_TOK) {
        float4 v = *(const float4*)(x + base);
        o.x = f2bf(v.x); o.y = f2bf(v.y); o.z = f2bf(v.z); o.w = f2bf(v.w);
    } else {
        o.x = 0; o.y = 0; o.z = 0; o.w = 0;
    }
    *(ushort4*)(xb + base) = o;
}

// ------------- fused weight transpose: fp32 [e][k][n] -> bf16 [e][n][k] -------------
#define TSP 68
__global__ void transpose_cvt_k(const float* __restrict__ W0, const float* __restrict__ W1,
                                const float* __restrict__ W2,
                                unsigned short* __restrict__ T0, unsigned short* __restrict__ T1,
                                unsigned short* __restrict__ T2) {
    __shared__ unsigned short s[64 * TSP];
    int zz = blockIdx.z;                 // 0..47
    int which = zz >> 4, e = zz & 15;
    const float* W = (which == 0) ? W0 : (which == 1) ? W1 : W2;
    unsigned short* T = (which == 0) ? T0 : (which == 1) ? T1 : T2;
    const float* Wp = W + (size_t)e * DIM * HID;
    unsigned short* Tp = T + (size_t)e * DIM * HID;
    int k0 = blockIdx.y * 64, n0 = blockIdx.x * 64;
    int tid = threadIdx.x;
    int tx = tid & 15, ty = tid >> 4;
    #pragma unroll
    for (int i = 0; i < 4; ++i) {
        int k = ty + i * 16;
        float4 v = *(const float4*)(Wp + (size_t)(k0 + k) * 1024 + n0 + tx * 4);
        int nb = tx * 4;
        s[(nb + 0) * TSP + k] = f2bf(v.x);
        s[(nb + 1) * TSP + k] = f2bf(v.y);
        s[(nb + 2) * TSP + k] = f2bf(v.z);
        s[(nb + 3) * TSP + k] = f2bf(v.w);
    }
    __syncthreads();
    int n = tid >> 2, cseg = (tid & 3) * 16;
    union { ushort4 h[4]; uint4 q[2]; } u;
    #pragma unroll
    for (int j = 0; j < 4; ++j)
        u.h[j] = *(ushort4*)&s[n * TSP + cseg + 4 * j];
    unsigned short* orow = Tp + (size_t)(n0 + n) * 1024 + k0 + cseg;
    *(uint4*)(orow + 0) = u.q[0];
    *(uint4*)(orow + 8) = u.q[1];
}

// ---------------- router: logits, softmax, top-2 (one wave per token) ----------------
__global__ void router_k(const float* __restrict__ x, const float* __restrict__ rw,
                         int* __restrict__ route_e, float* __restrict__ route_w) {
    int t = blockIdx.x;
    int lane = threadIdx.x;
    const float* xr = x + (size_t)t * DIM + lane * 16;
    float4 xv0 = *(const float4*)(xr + 0);
    float4 xv1 = *(const float4*)(xr + 4);
    float4 xv2 = *(const float4*)(xr + 8);
    float4 xv3 = *(const float4*)(xr + 12);
    float xl[16] = {xv0.x, xv0.y, xv0.z, xv0.w, xv1.x, xv1.y, xv1.z, xv1.w,
                    xv2.x, xv2.y, xv2.z, xv2.w, xv3.x, xv3.y, xv3.z, xv3.w};
    float p[16];
    #pragma unroll
    for (int e = 0; e < 16; ++e) p[e] = 0.f;
    #pragma unroll
    for (int j = 0; j < 16; ++j) {
        const float4* rp = (const float4*)(rw + (size_t)(lane * 16 + j) * 16);
        float4 r0 = rp[0], r1 = rp[1], r2 = rp[2], r3 = rp[3];
        float xv = xl[j];
        p[0]  += xv * r0.x; p[1]  += xv * r0.y; p[2]  += xv * r0.z; p[3]  += xv * r0.w;
        p[4]  += xv * r1.x; p[5]  += xv * r1.y; p[6]  += xv * r1.z; p[7]  += xv * r1.w;
        p[8]  += xv * r2.x; p[9]  += xv * r2.y; p[10] += xv * r2.z; p[11] += xv * r2.w;
        p[12] += xv * r3.x; p[13] += xv * r3.y; p[14] += xv * r3.z; p[15] += xv * r3.w;
    }
    #pragma unroll
    for (int off = 32; off > 0; off >>= 1) {
        #pragma unroll
        for (int e = 0; e < 16; ++e) p[e] += __shfl_xor(p[e], off);
    }
    if (lane == 0) {
        float m = p[0];
        #pragma unroll
        for (int e = 1; e < 16; ++e) m = fmaxf(m, p[e]);
        float s = 0.f;
        #pragma unroll
        for (int e = 0; e < 16; ++e) s = s + __expf(p[e] - m);
        float v0 = -1e30f, v1 = -1e30f; int i0 = 0, i1 = 0;
        #pragma unroll
        for (int e = 0; e < 16; ++e) {
            float v = p[e];
            if (v > v0)      { v1 = v0; i1 = i0; v0 = v; i0 = e; }
            else if (v > v1) { v1 = v;  i1 = e; }
        }
        route_e[t*2+0] = i0;  route_e[t*2+1] = i1;
        route_w[t*2+0] = __expf(v0 - m) / s;
        route_w[t*2+1] = __expf(v1 - m) / s;
    }
}

// ------- dispatch build: ballot rank/slot + inverse map smap + tile list -------
__global__ __launch_bounds__(1024)
void build_dispatch_k(const int* __restrict__ route_e, const float* __restrict__ route_w,
                      int* __restrict__ disp, int* __restrict__ smap, int* __restrict__ tmeta) {
    __shared__ unsigned char eidx[2 * T_TOK];
    __shared__ unsigned char keepf[2 * T_TOK];
    __shared__ int totals[NE];
    int tid = threadIdx.x;
    int wv = tid >> 6, lane = tid & 63;

    {   // route_e (8192 ints) -> bytes, coalesced
        int4 a = ((const int4*)route_e)[tid * 2];
        int4 b = ((const int4*)route_e)[tid * 2 + 1];
        unsigned int lo = (a.x & 0xff) | ((a.y & 0xff) << 8) | ((a.z & 0xff) << 16) | ((a.w & 0xff) << 24);
        unsigned int hi = (b.x & 0xff) | ((b.y & 0xff) << 8) | ((b.z & 0xff) << 16) | ((b.w & 0xff) << 24);
        uint2 pk; pk.x = lo; pk.y = hi;
        *(uint2*)(eidx + tid * 8) = pk;
    }
    for (int i = tid; i < 2 * T_TOK; i += 1024) smap[i] = -1;   // default: dropped
    __syncthreads();

    unsigned long long below = (lane == 0) ? 0ull : ((~0ull) >> (64 - lane));
    #pragma unroll
    for (int s = 0; s < 2; ++s) {      // keep = token-order rank in (e,k) stream < CAP
        int st = wv + s * 16;
        int e = st >> 1, k = st & 1;
        int run = 0;
        for (int base = 0; base < T_TOK; base += 64) {
            int t = base + lane;
            int hit = (eidx[t * 2 + k] == e);
            unsigned long long m = __ballot(hit);
            int rank = run + __popcll(m & below);
            if (hit) keepf[t * 2 + k] = (rank < CAP) ? 1 : 0;
            run += __popcll(m);
        }
    }
    __syncthreads();

    {   // slot = flat-order rank among kept entries of expert e (one wave per expert)
        int e = wv;
        int run = 0;
        for (int base = 0; base < 2 * T_TOK; base += 64) {
            int f = base + lane;
            int hit = (eidx[f] == e) && keepf[f];
            unsigned long long m = __ballot(hit);
            int slot = run + __popcll(m & below);
            if (hit) {
                disp[e * CBUF + slot] = f >> 1;
                smap[f] = e * CBUF + slot;
            }
            run += __popcll(m);
        }
        if (lane == 0) totals[e] = run;
    }
    __syncthreads();

    for (int i = tid; i < NE * CBUF; i += 1024) {   // pad unused slots -> zero row
        int e = i / CBUF, s = i - e * CBUF;
        if (s >= totals[e]) disp[i] = T_TOK;
    }

    if (tid == 0) {   // active-tile list
        int n = 0;
        for (int e = 0; e < NE; ++e) {
            int ntl = (totals[e] + BM - 1) / BM;
            for (int m = 0; m < ntl; ++m) { tmeta[4 + n] = (e << 8) | m; ++n; }
        }
        tmeta[0] = n;
    }
}

// ---------------- GEMM1: xe @ {gate,up} fused + SiLU -> hidden (bf16) ----------------
// Double-buffered global_load_lds pipeline: raw s_barrier (no compiler vmcnt(0)
// drain); tile k+1's DMA stays in flight through compute of tile k.
__global__ __launch_bounds__(256, 2)
void gemm1_k(const unsigned short* __restrict__ xb, const unsigned short* __restrict__ gt,
             const unsigned short* __restrict__ ut, const int* __restrict__ disp,
             const int* __restrict__ tmeta, unsigned short* __restrict__ hidden) {
    int slot = blockIdx.y;
    if (slot >= tmeta[0]) return;
    int pk = tmeta[4 + slot];
    int e = pk >> 8, mt = pk & 255;
    int m0 = mt * BM, n0 = blockIdx.x * BN;

    __shared__ unsigned short As[2 * BM * BK];
    __shared__ unsigned short Bg[2 * BN * BK];
    __shared__ unsigned short Bu[2 * BN * BK];
    __shared__ int tok[BM];
    int tid = threadIdx.x;
    if (tid < BM) tok[tid] = disp[e * CBUF + m0 + tid];
    __syncthreads();

    int lane = tid & 63, w = tid >> 6;
    int cg = (lane & 3) ^ ((lane >> 3) & 3);   // swizzled source chunk
    int rl = lane >> 2;
    int rA0 = w * 32 + rl, rA1 = rA0 + 16;
    const unsigned short* srcA0 = xb + (size_t)tok[rA0] * DIM + cg * 8;
    const unsigned short* srcA1 = xb + (size_t)tok[rA1] * DIM + cg * 8;
    const unsigned short* srcG0 = gt + ((size_t)e * HID + n0 + rA0) * DIM + cg * 8;
    const unsigned short* srcG1 = gt + ((size_t)e * HID + n0 + rA1) * DIM + cg * 8;
    const unsigned short* srcU0 = ut + ((size_t)e * HID + n0 + rA0) * DIM + cg * 8;
    const unsigned short* srcU1 = ut + ((size_t)e * HID + n0 + rA1) * DIM + cg * 8;
    unsigned short* dA0 = As + (w * 32) * BK;
    unsigned short* dA1 = As + (w * 32 + 16) * BK;
    unsigned short* dG0 = Bg + (w * 32) * BK;
    unsigned short* dG1 = Bg + (w * 32 + 16) * BK;
    unsigned short* dU0 = Bu + (w * 32) * BK;
    unsigned short* dU1 = Bu + (w * 32 + 16) * BK;

    int wm = w >> 1, wn = w & 1;
    int quad = lane >> 4, ln = lane & 15;
    int swq = quad ^ ((ln >> 1) & 3);          // read-side swizzle

    f32x4 zero4 = {0.f, 0.f, 0.f, 0.f};
    f32x4 accg[4][4], accu[4][4];
    #pragma unroll
    for (int i = 0; i < 4; ++i)
        #pragma unroll
        for (int j = 0; j < 4; ++j) { accg[i][j] = zero4; accu[i][j] = zero4; }

    // prologue: stage tile 0 into buffer 0
    async16(srcA0, dA0); async16(srcA1, dA1);
    async16(srcG0, dG0); async16(srcG1, dG1);
    async16(srcU0, dU0); async16(srcU1, dU1);

    for (int k0 = 0; k0 < DIM; k0 += BK) {
        int cur = (k0 >> 5) & 1;
        // wait own DMA (tile k), then barrier: tile k fully in LDS for all waves,
        // and all waves are done reading buffer cur^1 (last read one barrier ago).
        asm volatile("s_waitcnt vmcnt(0)\n\ts_barrier" ::: "memory");
        if (k0 + BK < DIM) {
            int nx = cur ^ 1, nk = k0 + BK;
            async16(srcA0 + nk, dA0 + nx * (BM * BK));
            async16(srcA1 + nk, dA1 + nx * (BM * BK));
            async16(srcG0 + nk, dG0 + nx * (BN * BK));
            async16(srcG1 + nk, dG1 + nx * (BN * BK));
            async16(srcU0 + nk, dU0 + nx * (BN * BK));
            async16(srcU1 + nk, dU1 + nx * (BN * BK));
        }
        const unsigned short* Ab = As + cur * (BM * BK);
        const unsigned short* Gb = Bg + cur * (BN * BK);
        const unsigned short* Ub = Bu + cur * (BN * BK);
        short8 af[4], bgf[4], buf2[4];
        #pragma unroll
        for (int i = 0; i < 4; ++i)
            af[i] = *(const short8*)(Ab + (wm * 64 + i * 16 + ln) * BK + swq * 8);
        #pragma unroll
        for (int j = 0; j < 4; ++j) {
            bgf[j]  = *(const short8*)(Gb + (wn * 64 + j * 16 + ln) * BK + swq * 8);
            buf2[j] = *(const short8*)(Ub + (wn * 64 + j * 16 + ln) * BK + swq * 8);
        }
        #pragma unroll
        for (int i = 0; i < 4; ++i)
            #pragma unroll
            for (int j = 0; j < 4; ++j) {
                accg[i][j] = __builtin_amdgcn_mfma_f32_16x16x32_bf16(af[i], bgf[j],  accg[i][j], 0, 0, 0);
                accu[i][j] = __builtin_amdgcn_mfma_f32_16x16x32_bf16(af[i], buf2[j], accu[i][j], 0, 0, 0);
            }
    }
    #pragma unroll
    for (int i = 0; i < 4; ++i) {
        #pragma unroll
        for (int r = 0; r < 4; ++r) {
            int row = m0 + wm * 64 + i * 16 + quad * 4 + r;
            unsigned short* hrow = hidden + ((size_t)e * CBUF + row) * HID + n0 + wn * 64 + ln;
            #pragma unroll
            for (int j = 0; j < 4; ++j) {
                float g = accg[i][j][r];
                float u = accu[i][j][r];
                float sg = g / (1.f + __expf(-g));
                hrow[j * 16] = f2bf(sg * u);
            }
        }
    }
}

// ---------------- GEMM2: hidden @ down -> ebuf (bf16, per expert slot) ----------------
__global__ __launch_bounds__(256, 2)
void gemm2_k(const unsigned short* __restrict__ hidden, const unsigned short* __restrict__ dt,
             const int* __restrict__ tmeta, unsigned short* __restrict__ ebuf) {
    int slot = blockIdx.y;
    if (slot >= tmeta[0]) return;
    int pk = tmeta[4 + slot];
    int e = pk >> 8, mt = pk & 255;
    int m0 = mt * BM, n0 = blockIdx.x * BN;

    __shared__ unsigned short As[2 * BM * BK];
    __shared__ unsigned short Bs[2 * BN * BK];
    int tid = threadIdx.x;

    int lane = tid & 63, w = tid >> 6;
    int cg = (lane & 3) ^ ((lane >> 3) & 3);
    int rl = lane >> 2;
    int rA0 = w * 32 + rl, rA1 = rA0 + 16;
    const unsigned short* srcA0 = hidden + ((size_t)e * CBUF + m0 + rA0) * HID + cg * 8;
    const unsigned short* srcA1 = hidden + ((size_t)e * CBUF + m0 + rA1) * HID + cg * 8;
    const unsigned short* srcB0 = dt + ((size_t)e * DIM + n0 + rA0) * HID + cg * 8;
    const unsigned short* srcB1 = dt + ((size_t)e * DIM + n0 + rA1) * HID + cg * 8;
    unsigned short* dA0 = As + (w * 32) * BK;
    unsigned short* dA1 = As + (w * 32 + 16) * BK;
    unsigned short* dB0 = Bs + (w * 32) * BK;
    unsigned short* dB1 = Bs + (w * 32 + 16) * BK;

    int wm = w >> 1, wn = w & 1;
    int quad = lane >> 4, ln = lane & 15;
    int swq = quad ^ ((ln >> 1) & 3);

    f32x4 zero4 = {0.f, 0.f, 0.f, 0.f};
    f32x4 acc[4][4];
    #pragma unroll
    for (int i = 0; i < 4; ++i)
        #pragma unroll
        for (int j = 0; j < 4; ++j) acc[i][j] = zero4;

    async16(srcA0, dA0); async16(srcA1, dA1);
    async16(srcB0, dB0); async16(srcB1, dB1);

    for (int k0 = 0; k0 < HID; k0 += BK) {
        int cur = (k0 >> 5) & 1;
        asm volatile("s_waitcnt vmcnt(0)\n\ts_barrier" ::: "memory");
        if (k0 + BK < HID) {
            int nx = cur ^ 1, nk = k0 + BK;
            async16(srcA0 + nk, dA0 + nx * (BM * BK));
            async16(srcA1 + nk, dA1 + nx * (BM * BK));
            async16(srcB0 + nk, dB0 + nx * (BN * BK));
            async16(srcB1 + nk, dB1 + nx * (BN * BK));
        }
        const unsigned short* Ab = As + cur * (BM * BK);
        const unsigned short* Bb = Bs + cur * (BN * BK);
        short8 af[4], bf[4];
        #pragma unroll
        for (int i = 0; i < 4; ++i)
            af[i] = *(const short8*)(Ab + (wm * 64 + i * 16 + ln) * BK + swq * 8);
        #pragma unroll
        for (int j = 0; j < 4; ++j)
            bf[j] = *(const short8*)(Bb + (wn * 64 + j * 16 + ln) * BK + swq * 8);
        #pragma unroll
        for (int i = 0; i < 4; ++i)
            #pragma unroll
            for (int j = 0; j < 4; ++j)
                acc[i][j] = __builtin_amdgcn_mfma_f32_16x16x32_bf16(af[i], bf[j], acc[i][j], 0, 0, 0);
    }
    #pragma unroll
    for (int i = 0; i < 4; ++i) {
        #pragma unroll
        for (int r = 0; r < 4; ++r) {
            int row = m0 + wm * 64 + i * 16 + quad * 4 + r;
            unsigned short* erow = ebuf + ((size_t)e * CBUF + row) * DIM + n0 + wn * 64 + ln;
            #pragma unroll
            for (int j = 0; j < 4; ++j)
                erow[j * 16] = f2bf(acc[i][j][r]);
        }
    }
}

// ---------------- combine: out[t] = sum_k w[t,k] * ebuf[smap[t,k]] ----------------
__global__ __launch_bounds__(256)
void combine_k(const unsigned short* __restrict__ ebuf, const int* __restrict__ smap,
               const float* __restrict__ rwt, float* __restrict__ out) {
    int t = blockIdx.x * 2 + (threadIdx.x >> 7);
    int c = (threadIdx.x & 127) * 8;
    float acc[8];
    #pragma unroll
    for (int j = 0; j < 8; ++j) acc[j] = 0.f;
    #pragma unroll
    for (int k = 0; k < 2; ++k) {
        int sm = smap[t * 2 + k];
        if (sm >= 0) {
            float wgt = rwt[t * 2 + k];
            uint4 rv = *(const uint4*)(ebuf + (size_t)sm * DIM + c);
            unsigned int d[4] = {rv.x, rv.y, rv.z, rv.w};
            #pragma unroll
            for (int q = 0; q < 4; ++q) {
                acc[q * 2 + 0] += wgt * __uint_as_float(d[q] << 16);
                acc[q * 2 + 1] += wgt * __uint_as_float(d[q] & 0xffff0000u);
            }
        }
    }
    float4 o0 = {acc[0], acc[1], acc[2], acc[3]};
    float4 o1 = {acc[4], acc[5], acc[6], acc[7]};
    float* orow = out + (size_t)t * DIM + c;
    *(float4*)(orow + 0) = o0;
    *(float4*)(orow + 4) = o1;
}

extern "C" void kernel_launch(void* const* d_in, const int* in_sizes, int n_in,
                              void* d_out, int out_size, void* d_ws, size_t ws_size,
                              hipStream_t stream) {
    const float* x  = (const float*)d_in[0];   // (2,2048,1024)
    const float* rw = (const float*)d_in[1];   // (1024,16)
    const float* gw = (const float*)d_in[2];   // (16,1024,1024) [e][d][h]
    const float* uw = (const float*)d_in[3];   // (16,1024,1024) [e][d][h]
    const float* dw = (const float*)d_in[4];   // (16,1024,1024) [e][h][d]
    float* out = (float*)d_out;

    char* ws = (char*)d_ws;
    size_t off = 0;
    auto alloc = [&](size_t bytes) { void* p = ws + off; off += (bytes + 255) & ~(size_t)255; return p; };
    unsigned short* xb  = (unsigned short*)alloc((size_t)(T_TOK + 1) * DIM * 2);
    unsigned short* gt  = (unsigned short*)alloc((size_t)NE * DIM * HID * 2);  // [e][h][d]
    unsigned short* ut  = (unsigned short*)alloc((size_t)NE * DIM * HID * 2);  // [e][h][d]
    unsigned short* dtw = (unsigned short*)alloc((size_t)NE * DIM * HID * 2);  // [e][d][h]
    unsigned short* hid = (unsigned short*)alloc((size_t)NE * CBUF * HID * 2);
    int*   disp   = (int*)alloc((size_t)NE * CBUF * 4);
    int*   smap   = (int*)alloc((size_t)T_TOK * 2 * 4);
    int*   tmeta  = (int*)alloc((4 + MAXTILE) * 4);
    int*   re     = (int*)alloc((size_t)T_TOK * 2 * 4);
    float* rwt    = (float*)alloc((size_t)T_TOK * 2 * 4);
    // ebuf (40 MB) aliases gt+ut (64 MB): gate/up weights are dead after gemm1.
    unsigned short* ebuf = gt;
    (void)ws_size; (void)in_sizes; (void)n_in;

    convert_x_k<<<T_TOK + 1, 256, 0, stream>>>(x, xb);
    transpose_cvt_k<<<dim3(16, 16, 48), 256, 0, stream>>>(gw, uw, dw, gt, ut, dtw);
    router_k<<<T_TOK, 64, 0, stream>>>(x, rw, re, rwt);
    build_dispatch_k<<<1, 1024, 0, stream>>>(re, rwt, disp, smap, tmeta);
    gemm1_k<<<dim3(HID / BN, MAXTILE), 256, 0, stream>>>(xb, gt, ut, disp, tmeta, hid);
    gemm2_k<<<dim3(DIM / BN, MAXTILE), 256, 0, stream>>>(hid, dtw, tmeta, ebuf);
    combine_k<<<T_TOK / 2, 256, 0, stream>>>(ebuf, smap, rwt, out);
}